// Round 12
// baseline (67.488 us; speedup 1.0000x reference)
//
#include <hip/hip_runtime.h>
#include <hip/hip_bf16.h>

// RotatedEmbedding: out[m,:] = W[ids[m],:] @ R  (M=16384, K=N=1024)
// Two-stage (fusion rejected empirically r1/r2/r5/r6/r8).
// prep (r7-exact): R->RT bf16 transposed (1024 blks) || gather W->G bf16 (2048).
// GEMM: 256x128 tile, BK=32, 4 waves (wave-tile 128x64 -> keeps r7's MFMA/LDS
//   amortization), A+B double-buffered = 48 KB LDS -> 2 blocks/CU (grid 512):
//   epilogue/prologue/drain overlap via cross-block TLP (m114). T3-minimum
//   2-phase sync (STAGE next -> compute -> vmcnt(0)+lgkm(0) -> barrier).
//   2-bit XOR slot swizzle both-sides (rule #21, 2-way = free). m-major
//   XCD-bijective swizzle (T1): XCD's A-panel = 4 MB = L2-resident.

typedef __attribute__((ext_vector_type(4))) float f32x4;
typedef __attribute__((ext_vector_type(8))) short s16x8;
typedef __attribute__((ext_vector_type(2))) int i32x2;

#define DIM 1024
#define NTK 32  // K-tiles (BK=32)

__device__ __forceinline__ short f2bf(float f) {
  unsigned u = __float_as_uint(f);
  unsigned r = (u + 0x7FFFu + ((u >> 16) & 1u)) >> 16;  // RNE
  return (short)r;
}

__device__ __forceinline__ void gload_lds16(const void* g, void* l) {
  __builtin_amdgcn_global_load_lds((const __attribute__((address_space(1))) void*)g,
                                   (__attribute__((address_space(3))) void*)l, 16, 0, 0);
}

// blocks [0,1024): R [K][N] f32 -> RT [N][K] bf16; [1024,3072): gather G rows.
__global__ __launch_bounds__(256) void prep_kernel(const float* __restrict__ R,
                                                   short* __restrict__ RT,
                                                   const float* __restrict__ W,
                                                   const int* __restrict__ ids,
                                                   short* __restrict__ G) {
  const int b = blockIdx.x;
  const int t = threadIdx.x;
  if (b < 1024) {
    __shared__ float tile[32][33];
    const int bx = b & 31, by = b >> 5;
    const int tx = t & 31, ty = t >> 5;
#pragma unroll
    for (int i = 0; i < 4; ++i)
      tile[ty + i * 8][tx] = R[(size_t)(by * 32 + ty + i * 8) * DIM + bx * 32 + tx];
    __syncthreads();
#pragma unroll
    for (int i = 0; i < 4; ++i)
      RT[(size_t)(bx * 32 + ty + i * 8) * DIM + by * 32 + tx] = f2bf(tile[tx][ty + i * 8]);
  } else {  // G[m][k] = bf16(W[ids[m]][k]), coalesced f32x4 -> 4xbf16
    const int tid = (b - 1024) * 256 + t;
#pragma unroll
    for (int i = 0; i < 8; ++i) {
      const int g = tid + i * (2048 * 256);
      const int row = g >> 8;
      const int c4 = (g & 255) << 2;
      const f32x4 v = *(const f32x4*)(W + (size_t)ids[row] * DIM + c4);
      i32x2 p;
      p[0] = (int)(unsigned short)f2bf(v[0]) | ((int)f2bf(v[1]) << 16);
      p[1] = (int)(unsigned short)f2bf(v[2]) | ((int)f2bf(v[3]) << 16);
      *(i32x2*)(G + (size_t)g * 4) = p;
    }
  }
}

// GEMM: out[M,N] = G[M,K] * RT[N,K]^T. Grid 512 blocks x 256 threads.
// Dynamic LDS 49152 B: A dbuf 2 x 16384 @0; B dbuf 2 x 8192 @32768.
// Tile rows are 64 B (32 bf16 = BK); 16B slot s of row r holds logical
// chunk s ^ (r&3) ^ ((r>>2)&3)  [pre-swizzled source, rule #21].
__global__ __launch_bounds__(256, 2) void rot_embed_gemm(const short* __restrict__ G,
                                                         const short* __restrict__ RT,
                                                         float* __restrict__ out) {
  extern __shared__ char smem[];

  const int t = threadIdx.x;
  const int b = blockIdx.x;
  // T1: XCD-bijective (512 % 8 == 0), m-major: XCD x owns m-tiles
  // [x*8,(x+1)*8) with all 8 n-siblings -> A-panel 4 MB L2-resident.
  const int swz = (b & 7) * 64 + (b >> 3);
  const int m0 = (swz >> 3) * 256;
  const int n0 = (swz & 7) * 128;

  const int lane = t & 63;
  const int w = t >> 6;               // wave 0..3
  const int wm = w >> 1, wn = w & 1;  // wave-tile 128x64 at (wm*128, wn*64)
  const int fr = lane & 15, fq = lane >> 4;

  char* const ldsA = smem;           // 2 x 16384
  char* const ldsB = smem + 32768;   // 2 x 8192

  // Staging: A instr j (0..3) covers rows j*64 + (t>>2); B instr j (0..1)
  // likewise. Logical chunk = (t&3) ^ ((t>>2)&3) ^ ((t>>4)&3)  (j*64, w*16
  // row offsets vanish mod the XOR bits).
  const int scol = ((t & 3) ^ ((t >> 2) & 3) ^ ((t >> 4) & 3)) * 8;  // bf16 elems
  const short* gA = G + (size_t)(m0 + (t >> 2)) * DIM + scol;
  const short* gB = RT + (size_t)(n0 + (t >> 2)) * DIM + scol;
  const int dOff = w * 1024;  // wave-uniform dest base (+lane*16 by HW)

#define STG(buf, kt)                                                        \
  {                                                                         \
    _Pragma("unroll") for (int j = 0; j < 4; ++j)                           \
        gload_lds16(gA + (size_t)(j * 64) * DIM + (kt) * 32,                \
                    ldsA + (buf) * 16384 + j * 4096 + dOff);                \
    _Pragma("unroll") for (int j = 0; j < 2; ++j)                           \
        gload_lds16(gB + (size_t)(j * 64) * DIM + (kt) * 32,                \
                    ldsB + (buf) * 8192 + j * 4096 + dOff);                 \
  }

  f32x4 acc[8][4];
#pragma unroll
  for (int i = 0; i < 8; ++i)
#pragma unroll
    for (int j = 0; j < 4; ++j) acc[i][j] = (f32x4)0.0f;

  // read slot (loop-invariant): chunk fq of row r; (r&3)=fr&3, ((r>>2)&3)=(fr>>2)&3
  const int sl = (fq ^ (fr & 3) ^ ((fr >> 2) & 3)) << 4;

  // prologue: stage tile 0, drain, barrier
  STG(0, 0);
  asm volatile("s_waitcnt vmcnt(0)" ::: "memory");
  __builtin_amdgcn_s_barrier();

  for (int kt = 0; kt < NTK; ++kt) {
    const int buf = kt & 1;
    // T3-minimum: issue next tile's stage BEFORE compute (latency hides under MFMA)
    if (kt + 1 < NTK) STG(buf ^ 1, kt + 1);

    const char* A = ldsA + buf * 16384;
    const char* B = ldsB + buf * 8192;
    s16x8 af[8], bfv[4];
#pragma unroll
    for (int i = 0; i < 8; ++i)
      af[i] = *(const s16x8*)(A + (wm * 128 + i * 16 + fr) * 64 + sl);
#pragma unroll
    for (int i = 0; i < 4; ++i)
      bfv[i] = *(const s16x8*)(B + (wn * 64 + i * 16 + fr) * 64 + sl);
    __builtin_amdgcn_s_setprio(1);
#pragma unroll
    for (int mi = 0; mi < 8; ++mi)
#pragma unroll
      for (int nj = 0; nj < 4; ++nj)
        acc[mi][nj] = __builtin_amdgcn_mfma_f32_16x16x32_bf16(af[mi], bfv[nj], acc[mi][nj], 0, 0, 0);
    __builtin_amdgcn_s_setprio(0);

    // next tile landed + my reads of buf done -> safe to flip
    asm volatile("s_waitcnt vmcnt(0) lgkmcnt(0)" ::: "memory");
    __builtin_amdgcn_s_barrier();
  }

  // epilogue: D col=lane&15, row=(lane>>4)*4+reg (m89-verified); NT stores
#pragma unroll
  for (int mi = 0; mi < 8; ++mi)
#pragma unroll
    for (int nj = 0; nj < 4; ++nj) {
      float* op = out + (size_t)(m0 + wm * 128 + mi * 16 + fq * 4) * DIM +
                  (n0 + wn * 64 + nj * 16 + fr);
#pragma unroll
      for (int r = 0; r < 4; ++r)
        __builtin_nontemporal_store(acc[mi][nj][r], op + (size_t)r * DIM);
    }
#undef STG
}

extern "C" void kernel_launch(void* const* d_in, const int* in_sizes, int n_in,
                              void* d_out, int out_size, void* d_ws, size_t ws_size,
                              hipStream_t stream) {
  const int* ids = (const int*)d_in[0];    // [4,4096] int32
  const float* W = (const float*)d_in[1];  // [50257,1024] f32
  const float* R = (const float*)d_in[2];  // [1024,1024] f32
  float* out = (float*)d_out;              // [4,4096,1024] f32
  short* RT = (short*)d_ws;                // 2 MB bf16 R^T
  short* G = (short*)d_ws + (size_t)DIM * DIM;  // 32 MB bf16 gathered rows

  prep_kernel<<<dim3(3072), dim3(256), 0, stream>>>(R, RT, W, ids, G);
  rot_embed_gemm<<<dim3(512), dim3(256), 49152, stream>>>(G, RT, out);
}

// Round 13
// 64.264 us; speedup vs baseline: 1.0502x; 1.0502x over previous
//
#include <hip/hip_runtime.h>
#include <hip/hip_bf16.h>

// RotatedEmbedding: out[m,:] = W[ids[m],:] @ R  (M=16384, K=N=1024)
// Two-stage (fusion rejected r1/r2/r5/r6/r8; small-tile occupancy variants
// rejected r10/r11/r12). prep = r7-exact. GEMM = r7 geometry (256x256, BK=64,
// 8 waves 2x4, wave-tile 128x64, A 3-ring + B 2-ring = 160 KB, counted
// vmcnt(4) ledger) + m201-style 8-phase interleave: per K-tile 4 sub-phases
// {ds-read subtile (4-8 b128) -> 2 gloads -> barrier -> lgkm0 -> setprio ->
// 16-MFMA quadrant -> barrier}. Counted vmcnt once per tile at SP4 (T4).

typedef __attribute__((ext_vector_type(4))) float f32x4;
typedef __attribute__((ext_vector_type(8))) short s16x8;
typedef __attribute__((ext_vector_type(2))) int i32x2;

#define DIM 1024
#define NT 16  // K-tiles (BK=64)

__device__ __forceinline__ short f2bf(float f) {
  unsigned u = __float_as_uint(f);
  unsigned r = (u + 0x7FFFu + ((u >> 16) & 1u)) >> 16;  // RNE
  return (short)r;
}

__device__ __forceinline__ void gload_lds16(const void* g, void* l) {
  __builtin_amdgcn_global_load_lds((const __attribute__((address_space(1))) void*)g,
                                   (__attribute__((address_space(3))) void*)l, 16, 0, 0);
}

// blocks [0,1024): R [K][N] f32 -> RT [N][K] bf16; [1024,3072): gather G rows.
__global__ __launch_bounds__(256) void prep_kernel(const float* __restrict__ R,
                                                   short* __restrict__ RT,
                                                   const float* __restrict__ W,
                                                   const int* __restrict__ ids,
                                                   short* __restrict__ G) {
  const int b = blockIdx.x;
  const int t = threadIdx.x;
  if (b < 1024) {
    __shared__ float tile[32][33];
    const int bx = b & 31, by = b >> 5;
    const int tx = t & 31, ty = t >> 5;
#pragma unroll
    for (int i = 0; i < 4; ++i)
      tile[ty + i * 8][tx] = R[(size_t)(by * 32 + ty + i * 8) * DIM + bx * 32 + tx];
    __syncthreads();
#pragma unroll
    for (int i = 0; i < 4; ++i)
      RT[(size_t)(bx * 32 + ty + i * 8) * DIM + by * 32 + tx] = f2bf(tile[tx][ty + i * 8]);
  } else {  // G[m][k] = bf16(W[ids[m]][k]), coalesced f32x4 -> 4xbf16
    const int tid = (b - 1024) * 256 + t;
#pragma unroll
    for (int i = 0; i < 8; ++i) {
      const int g = tid + i * (2048 * 256);
      const int row = g >> 8;
      const int c4 = (g & 255) << 2;
      const f32x4 v = *(const f32x4*)(W + (size_t)ids[row] * DIM + c4);
      i32x2 p;
      p[0] = (int)(unsigned short)f2bf(v[0]) | ((int)f2bf(v[1]) << 16);
      p[1] = (int)(unsigned short)f2bf(v[2]) | ((int)f2bf(v[3]) << 16);
      *(i32x2*)(G + (size_t)g * 4) = p;
    }
  }
}

// GEMM: out[M,N] = G[M,K] * RT[N,K]^T. Grid 256 x 512 threads.
// Dynamic LDS 160 KB: A ring 3 x 32768 @0; B ring 2 x 32768 @98304.
// Tile rows 128 B (64 bf16 = BK); 16B slot s of row r holds chunk s^(r&7)
// [pre-swizzled gload source, rule #21] -> uniform-bank b128 reads.
__global__ __launch_bounds__(512, 2) void rot_embed_gemm(const short* __restrict__ G,
                                                         const short* __restrict__ RT,
                                                         float* __restrict__ out) {
  extern __shared__ char smem[];

  const int t = threadIdx.x;
  const int b = blockIdx.x;
  // T1: XCD-bijective (256 blocks): XCD x -> m-panels [x*8,(x+1)*8), all 4 n
  const int swz = (b & 7) * 32 + (b >> 3);
  const int m0 = (swz >> 2) * 256;
  const int n0 = (swz & 3) * 256;

  const int lane = t & 63;
  const int w = t >> 6;
  const int wm = w >> 2, wn = w & 3;  // wave-tile 128x64 at (wm*128, wn*64)
  const int fr = lane & 15, fq = lane >> 4;

  char* const ldsA = smem;           // 3 x 32768
  char* const ldsB = smem + 98304;   // 2 x 32768

  // Staging (r7-proven): instr j covers LDS rows j*64 + w*8 + (lane>>3),
  // slot lane&7; pre-swizzled source chunk = (lane&7) ^ (lane>>3).
  const int srow = w * 8 + (lane >> 3);
  const int sch = ((lane & 7) ^ (lane >> 3)) * 8;
  const short* gA = G + (size_t)(m0 + srow) * DIM + sch;
  const short* gB = RT + (size_t)(n0 + srow) * DIM + sch;
  const int ldsOff = w * 1024;

#define STA2(buf, kt, j0)                                                   \
  {                                                                         \
    gload_lds16(gA + (size_t)(j0) * 64 * DIM + (kt) * 64,                   \
                ldsA + (buf) * 32768 + (j0) * 8192 + ldsOff);               \
    gload_lds16(gA + (size_t)((j0) + 1) * 64 * DIM + (kt) * 64,             \
                ldsA + (buf) * 32768 + ((j0) + 1) * 8192 + ldsOff);         \
  }
#define STB2(buf, kt, j0)                                                   \
  {                                                                         \
    gload_lds16(gB + (size_t)(j0) * 64 * DIM + (kt) * 64,                   \
                ldsB + (buf) * 32768 + (j0) * 8192 + ldsOff);               \
    gload_lds16(gB + (size_t)((j0) + 1) * 64 * DIM + (kt) * 64,             \
                ldsB + (buf) * 32768 + ((j0) + 1) * 8192 + ldsOff);         \
  }
#define LDA4(A, rowbase, sl)                                                \
  {                                                                         \
    _Pragma("unroll") for (int i = 0; i < 4; ++i)                           \
        af[i] = *(const s16x8*)((A) + ((rowbase) + i * 16 + fr) * 128 + (sl)); \
  }
#define LDB4(B, sl)                                                         \
  {                                                                         \
    _Pragma("unroll") for (int i = 0; i < 4; ++i)                           \
        bfv[i] = *(const s16x8*)((B) + (wn * 64 + i * 16 + fr) * 128 + (sl)); \
  }
#define MFMA16(h)                                                           \
  {                                                                         \
    __builtin_amdgcn_s_setprio(1);                                          \
    _Pragma("unroll") for (int mi = 0; mi < 4; ++mi)                        \
        _Pragma("unroll") for (int nj = 0; nj < 4; ++nj)                    \
            acc[(h) * 4 + mi][nj] = __builtin_amdgcn_mfma_f32_16x16x32_bf16( \
                af[mi], bfv[nj], acc[(h) * 4 + mi][nj], 0, 0, 0);           \
    __builtin_amdgcn_s_setprio(0);                                          \
  }
#define BAR __builtin_amdgcn_s_barrier()
#define LGKM0 asm volatile("s_waitcnt lgkmcnt(0)" ::: "memory")

  f32x4 acc[8][4];
#pragma unroll
  for (int i = 0; i < 8; ++i)
#pragma unroll
    for (int j = 0; j < 4; ++j) acc[i][j] = (f32x4)0.0f;

  // prologue: A0(4), B0(4), A1(4) -> 12 in flight; vmcnt(4) = tile 0 landed
  STA2(0, 0, 0); STA2(0, 0, 2);
  STB2(0, 0, 0); STB2(0, 0, 2);
  STA2(1, 1, 0); STA2(1, 1, 2);
  asm volatile("s_waitcnt vmcnt(4)" ::: "memory");
  BAR;

  for (int kt = 0; kt < NT; ++kt) {
    const char* A = ldsA + (kt % 3) * 32768;
    const char* B = ldsB + (kt & 1) * 32768;
    const int sl0 = (fq ^ (fr & 7)) << 4;        // kk0 chunks 0..3
    const int sl1 = ((fq + 4) ^ (fr & 7)) << 4;  // kk1 chunks 4..7
    s16x8 af[4], bfv[4];

    // ---- SP1: h0 x kk0 ----
    LDA4(A, wm * 128, sl0);
    LDB4(B, sl0);
    if (kt + 1 < NT) STB2((kt + 1) & 1, kt + 1, 0);
    BAR; LGKM0;
    MFMA16(0);
    BAR;

    // ---- SP2: h1 x kk0 (bfv reused) ----
    LDA4(A, wm * 128 + 64, sl0);
    if (kt + 1 < NT) STB2((kt + 1) & 1, kt + 1, 2);
    BAR; LGKM0;
    MFMA16(1);
    BAR;

    // ---- SP3: h0 x kk1 ----
    LDA4(A, wm * 128, sl1);
    LDB4(B, sl1);
    if (kt + 2 < NT) STA2((kt + 2) % 3, kt + 2, 0);
    BAR; LGKM0;
    MFMA16(0);
    BAR;

    // ---- SP4: h1 x kk1 + counted vmcnt (tile kt+1 confirmed) ----
    LDA4(A, wm * 128 + 64, sl1);
    if (kt + 2 < NT) STA2((kt + 2) % 3, kt + 2, 2);
    if (kt + 2 < NT)
      asm volatile("s_waitcnt vmcnt(4)" ::: "memory");  // leaves STA(kt+2)
    else if (kt + 1 < NT)
      asm volatile("s_waitcnt vmcnt(0)" ::: "memory");
    BAR; LGKM0;
    MFMA16(1);
    BAR;
  }

  // epilogue: D col=lane&15, row=(lane>>4)*4+reg (m89-verified); NT stores
#pragma unroll
  for (int mi = 0; mi < 8; ++mi)
#pragma unroll
    for (int nj = 0; nj < 4; ++nj) {
      float* op = out + (size_t)(m0 + wm * 128 + mi * 16 + fq * 4) * DIM +
                  (n0 + wn * 64 + nj * 16 + fr);
#pragma unroll
      for (int r = 0; r < 4; ++r)
        __builtin_nontemporal_store(acc[mi][nj][r], op + (size_t)r * DIM);
    }
#undef STA2
#undef STB2
#undef LDA4
#undef LDB4
#undef MFMA16
#undef BAR
#undef LGKM0
}

extern "C" void kernel_launch(void* const* d_in, const int* in_sizes, int n_in,
                              void* d_out, int out_size, void* d_ws, size_t ws_size,
                              hipStream_t stream) {
  const int* ids = (const int*)d_in[0];    // [4,4096] int32
  const float* W = (const float*)d_in[1];  // [50257,1024] f32
  const float* R = (const float*)d_in[2];  // [1024,1024] f32
  float* out = (float*)d_out;              // [4,4096,1024] f32
  short* RT = (short*)d_ws;                // 2 MB bf16 R^T
  short* G = (short*)d_ws + (size_t)DIM * DIM;  // 32 MB bf16 gathered rows

  prep_kernel<<<dim3(3072), dim3(256), 0, stream>>>(R, RT, W, ids, G);
  rot_embed_gemm<<<dim3(256), dim3(512), 163840, stream>>>(G, RT, out);
}